// Round 1
// baseline (584.588 us; speedup 1.0000x reference)
//
#include <hip/hip_runtime.h>

typedef __attribute__((ext_vector_type(8))) short bf16x8;
typedef __attribute__((ext_vector_type(4))) short short4v;
typedef __attribute__((ext_vector_type(4))) float f32x4;
typedef __attribute__((ext_vector_type(4))) float float4v;

__device__ __forceinline__ unsigned short f2bf(float x) {
    unsigned u = __float_as_uint(x);
    return (unsigned short)((u + 0x7fffu + ((u >> 16) & 1u)) >> 16);
}
__device__ __forceinline__ float bf2f(unsigned short b) {
    return __uint_as_float(((unsigned)b) << 16);
}
__device__ __forceinline__ f32x4 mfma16(bf16x8 a, bf16x8 b, f32x4 c) {
    return __builtin_amdgcn_mfma_f32_16x16x32_bf16(a, b, c, 0, 0, 0);
}

// ------------------------------------------------------------------
// GEMM: Y[M,N] = X[M,K] @ W[N,K]^T + bias ; M=4096, N=K=1024
// MODE 0: X f32 -> bf16, 1 MFMA, out bf16        (V projection)
// MODE 1: X,W f32 -> hi/lo split, 3 MFMA, out f32 (Q,K projections)
// MODE 2: X bf16 passthrough, 1 MFMA, out f32     (output projection)
// ------------------------------------------------------------------
constexpr int GK  = 1024;
constexpr int BM  = 128, BN = 128, BK = 64;
constexpr int LDT = BK + 8;   // 72 shorts = 144 B row stride (16B-aligned)

template<int MODE>
__global__ __launch_bounds__(256)
void gemm_kernel(const void* __restrict__ Ap, const float* __restrict__ Wp,
                 const float* __restrict__ bias, void* __restrict__ Op)
{
    __shared__ short smem[(MODE == 1 ? 4 : 2) * BM * LDT];
    short* Ah = smem;
    short* Al = smem + BM * LDT;                       // MODE 1 only
    short* Bh = smem + (MODE == 1 ? 2 : 1) * BM * LDT;
    short* Bl = smem + 3 * BM * LDT;                   // MODE 1 only

    const int tid  = threadIdx.x;
    const int lane = tid & 63;
    const int wv   = tid >> 6;
    const int lr   = lane & 15, lg = lane >> 4;
    const int m0 = blockIdx.y * BM, n0 = blockIdx.x * BN;
    const int wm = (wv >> 1) * 64, wn = (wv & 1) * 64;

    f32x4 acc[4][4] = {};

    const int c4 = tid & 15, r16 = tid >> 4;
    const int c8 = tid & 7,  r32 = tid >> 3;

    for (int k0 = 0; k0 < GK; k0 += BK) {
        // ---- stage A tile ----
        if (MODE == 2) {
            const unsigned short* A = (const unsigned short*)Ap;
            #pragma unroll
            for (int i = 0; i < 4; ++i) {
                int r = r32 + 32 * i;
                bf16x8 v = *(const bf16x8*)(A + (size_t)(m0 + r) * GK + k0 + c8 * 8);
                *(bf16x8*)(Ah + r * LDT + c8 * 8) = v;
            }
        } else {
            const float* A = (const float*)Ap;
            #pragma unroll
            for (int i = 0; i < 8; ++i) {
                int r = r16 + 16 * i;
                float4v v = *(const float4v*)(A + (size_t)(m0 + r) * GK + k0 + c4 * 4);
                short4v hv, lv;
                #pragma unroll
                for (int j = 0; j < 4; ++j) {
                    unsigned short hb = f2bf(v[j]);
                    hv[j] = (short)hb;
                    lv[j] = (short)f2bf(v[j] - bf2f(hb));
                }
                *(short4v*)(Ah + r * LDT + c4 * 4) = hv;
                if (MODE == 1) *(short4v*)(Al + r * LDT + c4 * 4) = lv;
            }
        }
        // ---- stage B (W) tile ----
        {
            #pragma unroll
            for (int i = 0; i < 8; ++i) {
                int r = r16 + 16 * i;
                float4v v = *(const float4v*)(Wp + (size_t)(n0 + r) * GK + k0 + c4 * 4);
                short4v hv, lv;
                #pragma unroll
                for (int j = 0; j < 4; ++j) {
                    unsigned short hb = f2bf(v[j]);
                    hv[j] = (short)hb;
                    lv[j] = (short)f2bf(v[j] - bf2f(hb));
                }
                *(short4v*)(Bh + r * LDT + c4 * 4) = hv;
                if (MODE == 1) *(short4v*)(Bl + r * LDT + c4 * 4) = lv;
            }
        }
        __syncthreads();

        #pragma unroll
        for (int ks = 0; ks < 2; ++ks) {
            bf16x8 af[4], bfr[4], afl[4], bfl[4];
            #pragma unroll
            for (int mi = 0; mi < 4; ++mi) {
                const int row = wm + mi * 16 + lr;
                af[mi] = *(const bf16x8*)(Ah + row * LDT + ks * 32 + lg * 8);
                if (MODE == 1) afl[mi] = *(const bf16x8*)(Al + row * LDT + ks * 32 + lg * 8);
            }
            #pragma unroll
            for (int ni = 0; ni < 4; ++ni) {
                const int row = wn + ni * 16 + lr;
                bfr[ni] = *(const bf16x8*)(Bh + row * LDT + ks * 32 + lg * 8);
                if (MODE == 1) bfl[ni] = *(const bf16x8*)(Bl + row * LDT + ks * 32 + lg * 8);
            }
            #pragma unroll
            for (int mi = 0; mi < 4; ++mi)
                #pragma unroll
                for (int ni = 0; ni < 4; ++ni) {
                    acc[mi][ni] = mfma16(af[mi], bfr[ni], acc[mi][ni]);
                    if (MODE == 1) {
                        acc[mi][ni] = mfma16(af[mi],  bfl[ni], acc[mi][ni]);
                        acc[mi][ni] = mfma16(afl[mi], bfr[ni], acc[mi][ni]);
                    }
                }
        }
        __syncthreads();
    }

    // ---- epilogue: D layout col=lane&15, row=(lane>>4)*4+reg ----
    #pragma unroll
    for (int mi = 0; mi < 4; ++mi)
        #pragma unroll
        for (int ni = 0; ni < 4; ++ni) {
            const int gr = m0 + wm + mi * 16 + lg * 4;
            const int gc = n0 + wn + ni * 16 + lr;
            const float bv = bias[gc];
            #pragma unroll
            for (int r = 0; r < 4; ++r) {
                float val = acc[mi][ni][r] + bv;
                if (MODE == 0)
                    ((unsigned short*)Op)[(size_t)(gr + r) * GK + gc] = f2bf(val);
                else
                    ((float*)Op)[(size_t)(gr + r) * GK + gc] = val;
            }
        }
}

// ------------------------------------------------------------------
// Flash attention: per block one (b,h) and 128 query rows.
// Q (f32) hi/lo split in regs; K (f32) hi/lo split in LDS; V bf16 in LDS^T.
// Scores = 3-MFMA split (high precision); PV plain bf16.
// ------------------------------------------------------------------
constexpr int SEQ = 2048, DMODEL = 1024, DK = 64, QT = 128, KTILE = 128;
constexpr int LKV = 72;    // K tile row stride (shorts)
constexpr int LVT = 144;   // V^T row stride
constexpr int LPP = 144;   // P row stride

__global__ __launch_bounds__(256)
void attn_kernel(const float* __restrict__ Qf, const float* __restrict__ Kf,
                 const unsigned short* __restrict__ Vb, unsigned short* __restrict__ Mrg)
{
    __shared__ short Khi[KTILE * LKV];
    __shared__ short Klo[KTILE * LKV];
    __shared__ short Vt[DK * LVT];
    __shared__ short Pl[4 * 32 * LPP];

    const int tid = threadIdx.x, lane = tid & 63, wv = tid >> 6;
    const int lr = lane & 15, lg = lane >> 4;
    const int qt = blockIdx.x, bh = blockIdx.y;
    const int b = bh >> 4, h = bh & 15;
    const size_t rowbase = (size_t)b * SEQ;
    const int col0 = h * DK;

    // Q fragments (hi/lo), loaded once, reused across all K tiles
    bf16x8 qh[2][2], ql[2][2];
    #pragma unroll
    for (int mi = 0; mi < 2; ++mi)
        #pragma unroll
        for (int ks = 0; ks < 2; ++ks) {
            const float* p = Qf + (rowbase + qt * QT + wv * 32 + mi * 16 + lr) * DMODEL
                           + col0 + ks * 32 + lg * 8;
            #pragma unroll
            for (int j = 0; j < 8; ++j) {
                float x = p[j];
                unsigned short hb = f2bf(x);
                qh[mi][ks][j] = (short)hb;
                ql[mi][ks][j] = (short)f2bf(x - bf2f(hb));
            }
        }

    f32x4 acc_o[2][4] = {};
    float m_run[2][4], l_run[2][4];
    #pragma unroll
    for (int mi = 0; mi < 2; ++mi)
        #pragma unroll
        for (int r = 0; r < 4; ++r) { m_run[mi][r] = -1e30f; l_run[mi][r] = 0.f; }

    const int c4 = tid & 15, r16 = tid >> 4;
    const int c8 = tid & 7,  r32 = tid >> 3;

    for (int kt = 0; kt < SEQ; kt += KTILE) {
        // stage K tile (hi/lo)
        #pragma unroll
        for (int i = 0; i < 8; ++i) {
            int r = r16 + 16 * i;
            float4v v = *(const float4v*)(Kf + (rowbase + kt + r) * DMODEL + col0 + c4 * 4);
            short4v hv, lv;
            #pragma unroll
            for (int j = 0; j < 4; ++j) {
                unsigned short hb = f2bf(v[j]);
                hv[j] = (short)hb;
                lv[j] = (short)f2bf(v[j] - bf2f(hb));
            }
            *(short4v*)(Khi + r * LKV + c4 * 4) = hv;
            *(short4v*)(Klo + r * LKV + c4 * 4) = lv;
        }
        // stage V tile transposed: Vt[d][key]
        #pragma unroll
        for (int i = 0; i < 4; ++i) {
            int r = r32 + 32 * i;
            bf16x8 v = *(const bf16x8*)(Vb + (rowbase + kt + r) * DMODEL + col0 + c8 * 8);
            #pragma unroll
            for (int j = 0; j < 8; ++j)
                Vt[(c8 * 8 + j) * LVT + r] = v[j];
        }
        __syncthreads();

        // scores S = (Q K^T): split 3-MFMA
        f32x4 s[2][8] = {};
        #pragma unroll
        for (int ks = 0; ks < 2; ++ks)
            #pragma unroll
            for (int ni = 0; ni < 8; ++ni) {
                bf16x8 kh = *(const bf16x8*)(Khi + (ni * 16 + lr) * LKV + ks * 32 + lg * 8);
                bf16x8 kl = *(const bf16x8*)(Klo + (ni * 16 + lr) * LKV + ks * 32 + lg * 8);
                #pragma unroll
                for (int mi = 0; mi < 2; ++mi) {
                    s[mi][ni] = mfma16(qh[mi][ks], kh, s[mi][ni]);
                    s[mi][ni] = mfma16(qh[mi][ks], kl, s[mi][ni]);
                    s[mi][ni] = mfma16(ql[mi][ks], kh, s[mi][ni]);
                }
            }

        // online softmax (rows live in 16-lane groups: row=(lane>>4)*4+reg)
        #pragma unroll
        for (int mi = 0; mi < 2; ++mi) {
            #pragma unroll
            for (int ni = 0; ni < 8; ++ni) s[mi][ni] *= 0.125f;
            float rmax[4];
            #pragma unroll
            for (int r = 0; r < 4; ++r) {
                float m = s[mi][0][r];
                #pragma unroll
                for (int ni = 1; ni < 8; ++ni) m = fmaxf(m, s[mi][ni][r]);
                #pragma unroll
                for (int msk = 1; msk < 16; msk <<= 1) m = fmaxf(m, __shfl_xor(m, msk));
                rmax[r] = m;
            }
            #pragma unroll
            for (int r = 0; r < 4; ++r) {
                float mnew  = fmaxf(m_run[mi][r], rmax[r]);
                float alpha = __expf(m_run[mi][r] - mnew);
                m_run[mi][r] = mnew;
                float rs = 0.f;
                #pragma unroll
                for (int ni = 0; ni < 8; ++ni) {
                    float pv = __expf(s[mi][ni][r] - mnew);
                    s[mi][ni][r] = pv;
                    rs += pv;
                }
                #pragma unroll
                for (int msk = 1; msk < 16; msk <<= 1) rs += __shfl_xor(rs, msk);
                l_run[mi][r] = l_run[mi][r] * alpha + rs;
                #pragma unroll
                for (int di = 0; di < 4; ++di) acc_o[mi][di][r] *= alpha;
                #pragma unroll
                for (int ni = 0; ni < 8; ++ni)
                    Pl[wv * 32 * LPP + (mi * 16 + lg * 4 + r) * LPP + ni * 16 + lr] =
                        (short)f2bf(s[mi][ni][r]);
            }
        }
        __syncthreads();

        // PV: O += P @ V
        #pragma unroll
        for (int ksv = 0; ksv < 4; ++ksv) {
            bf16x8 pf[2];
            #pragma unroll
            for (int mi = 0; mi < 2; ++mi)
                pf[mi] = *(const bf16x8*)(Pl + wv * 32 * LPP + (mi * 16 + lr) * LPP
                                          + ksv * 32 + lg * 8);
            #pragma unroll
            for (int di = 0; di < 4; ++di) {
                bf16x8 vf = *(const bf16x8*)(Vt + (di * 16 + lr) * LVT + ksv * 32 + lg * 8);
                #pragma unroll
                for (int mi = 0; mi < 2; ++mi)
                    acc_o[mi][di] = mfma16(pf[mi], vf, acc_o[mi][di]);
            }
        }
        __syncthreads();
    }

    // epilogue: O /= l, store merged [b*S + s][h*64 + d] as bf16
    #pragma unroll
    for (int mi = 0; mi < 2; ++mi)
        #pragma unroll
        for (int di = 0; di < 4; ++di) {
            const int grow = qt * QT + wv * 32 + mi * 16 + lg * 4;
            const int gc = col0 + di * 16 + lr;
            #pragma unroll
            for (int r = 0; r < 4; ++r) {
                float val = acc_o[mi][di][r] / l_run[mi][r];
                Mrg[(rowbase + grow + r) * DMODEL + gc] = f2bf(val);
            }
        }
}

// ------------------------------------------------------------------
extern "C" void kernel_launch(void* const* d_in, const int* in_sizes, int n_in,
                              void* d_out, int out_size, void* d_ws, size_t ws_size,
                              hipStream_t stream)
{
    const float* queries = (const float*)d_in[0];
    const float* keys    = (const float*)d_in[1];
    const float* values  = (const float*)d_in[2];
    const float* w_q = (const float*)d_in[3];
    const float* b_q = (const float*)d_in[4];
    const float* w_k = (const float*)d_in[5];
    const float* b_k = (const float*)d_in[6];
    const float* w_v = (const float*)d_in[7];
    const float* b_v = (const float*)d_in[8];
    const float* w_o = (const float*)d_in[9];
    const float* b_o = (const float*)d_in[10];

    const size_t NE = (size_t)4096 * 1024;
    float* Qb          = (float*)d_ws;               // 16 MiB f32
    float* Kb          = Qb + NE;                    // 16 MiB f32
    unsigned short* Vb = (unsigned short*)(Kb + NE); // 8 MiB bf16
    unsigned short* Mb = Vb + NE;                    // 8 MiB bf16 (merged attn)

    dim3 blk(256), gg(8, 32), ga(16, 32);
    hipLaunchKernelGGL((gemm_kernel<1>), gg, blk, 0, stream, queries, w_q, b_q, Qb);
    hipLaunchKernelGGL((gemm_kernel<1>), gg, blk, 0, stream, keys,    w_k, b_k, Kb);
    hipLaunchKernelGGL((gemm_kernel<0>), gg, blk, 0, stream, values,  w_v, b_v, Vb);
    hipLaunchKernelGGL(attn_kernel, ga, blk, 0, stream, Qb, Kb, Vb, Mb);
    hipLaunchKernelGGL((gemm_kernel<2>), gg, blk, 0, stream, Mb, w_o, b_o, (float*)d_out);
}

// Round 2
// 483.164 us; speedup vs baseline: 1.2099x; 1.2099x over previous
//
#include <hip/hip_runtime.h>

typedef __attribute__((ext_vector_type(8))) short bf16x8;
typedef __attribute__((ext_vector_type(4))) short short4v;
typedef __attribute__((ext_vector_type(4))) float f32x4;
typedef __attribute__((ext_vector_type(4))) float float4v;
typedef unsigned short ushort_t;

__device__ __forceinline__ unsigned short f2bf(float x) {
    unsigned u = __float_as_uint(x);
    return (unsigned short)((u + 0x7fffu + ((u >> 16) & 1u)) >> 16);
}
__device__ __forceinline__ float bf2f(unsigned short b) {
    return __uint_as_float(((unsigned)b) << 16);
}
__device__ __forceinline__ f32x4 mfma16(bf16x8 a, bf16x8 b, f32x4 c) {
    return __builtin_amdgcn_mfma_f32_16x16x32_bf16(a, b, c, 0, 0, 0);
}

constexpr int GK = 1024;   // K-dim of every GEMM

// ------------------------------------------------------------------
// Elementwise split: f32 -> (hi, lo) bf16 arrays. n4 = N/4.
// ------------------------------------------------------------------
__global__ __launch_bounds__(256)
void split_kernel(const float* __restrict__ in, ushort_t* __restrict__ hi,
                  ushort_t* __restrict__ lo, int n4)
{
    int i = blockIdx.x * blockDim.x + threadIdx.x;
    const int stride = gridDim.x * blockDim.x;
    for (; i < n4; i += stride) {
        float4v v = ((const float4v*)in)[i];
        short4v h, l;
        #pragma unroll
        for (int j = 0; j < 4; ++j) {
            unsigned short hb = f2bf(v[j]);
            h[j] = (short)hb;
            l[j] = (short)f2bf(v[j] - bf2f(hb));
        }
        ((short4v*)hi)[i] = h;
        ((short4v*)lo)[i] = l;
    }
}

// ------------------------------------------------------------------
// Split GEMM (Q/K projections): all inputs pre-split bf16.
// Y = X @ W^T + bias, 3-MFMA hi/lo, output written as hi/lo bf16.
// M=4096, N=K=1024. BM=128, BN=64, BK=64, 256 thr (4 waves).
// ------------------------------------------------------------------
constexpr int SBM = 128, SBN = 64, SLD = 72;  // 72 shorts = 144 B row stride

__global__ __launch_bounds__(256)
void gemm_split(const ushort_t* __restrict__ Ahi, const ushort_t* __restrict__ Alo,
                const ushort_t* __restrict__ Bhi, const ushort_t* __restrict__ Blo,
                const float* __restrict__ bias,
                ushort_t* __restrict__ Ohi, ushort_t* __restrict__ Olo)
{
    __shared__ alignas(16) short Ah[SBM * SLD], Al[SBM * SLD];
    __shared__ alignas(16) short Bh[SBN * SLD], Bl[SBN * SLD];

    const int tid = threadIdx.x, lane = tid & 63, wv = tid >> 6;
    const int lr = lane & 15, lg = lane >> 4;
    const int m0 = blockIdx.y * SBM, n0 = blockIdx.x * SBN;
    const int wm = (wv >> 1) * 64, wn = (wv & 1) * 32;

    f32x4 acc[4][2] = {};

    for (int k0 = 0; k0 < GK; k0 += 64) {
        #pragma unroll
        for (int i = 0; i < 4; ++i) {
            int idx = tid + 256 * i, r = idx >> 3, c = idx & 7;
            *(bf16x8*)(Ah + r * SLD + c * 8) =
                *(const bf16x8*)(Ahi + (size_t)(m0 + r) * GK + k0 + c * 8);
            *(bf16x8*)(Al + r * SLD + c * 8) =
                *(const bf16x8*)(Alo + (size_t)(m0 + r) * GK + k0 + c * 8);
        }
        #pragma unroll
        for (int i = 0; i < 2; ++i) {
            int idx = tid + 256 * i, r = idx >> 3, c = idx & 7;
            *(bf16x8*)(Bh + r * SLD + c * 8) =
                *(const bf16x8*)(Bhi + (size_t)(n0 + r) * GK + k0 + c * 8);
            *(bf16x8*)(Bl + r * SLD + c * 8) =
                *(const bf16x8*)(Blo + (size_t)(n0 + r) * GK + k0 + c * 8);
        }
        __syncthreads();

        #pragma unroll
        for (int ks = 0; ks < 2; ++ks) {
            bf16x8 af[4], afl[4], bfr[2], bfl[2];
            #pragma unroll
            for (int mi = 0; mi < 4; ++mi) {
                const int row = wm + mi * 16 + lr;
                af[mi]  = *(const bf16x8*)(Ah + row * SLD + ks * 32 + lg * 8);
                afl[mi] = *(const bf16x8*)(Al + row * SLD + ks * 32 + lg * 8);
            }
            #pragma unroll
            for (int ni = 0; ni < 2; ++ni) {
                const int row = wn + ni * 16 + lr;
                bfr[ni] = *(const bf16x8*)(Bh + row * SLD + ks * 32 + lg * 8);
                bfl[ni] = *(const bf16x8*)(Bl + row * SLD + ks * 32 + lg * 8);
            }
            #pragma unroll
            for (int mi = 0; mi < 4; ++mi)
                #pragma unroll
                for (int ni = 0; ni < 2; ++ni) {
                    acc[mi][ni] = mfma16(af[mi],  bfr[ni], acc[mi][ni]);
                    acc[mi][ni] = mfma16(af[mi],  bfl[ni], acc[mi][ni]);
                    acc[mi][ni] = mfma16(afl[mi], bfr[ni], acc[mi][ni]);
                }
        }
        __syncthreads();
    }

    #pragma unroll
    for (int mi = 0; mi < 4; ++mi)
        #pragma unroll
        for (int ni = 0; ni < 2; ++ni) {
            const int gr = m0 + wm + mi * 16 + lg * 4;
            const int gc = n0 + wn + ni * 16 + lr;
            const float bv = bias[gc];
            #pragma unroll
            for (int r = 0; r < 4; ++r) {
                float val = acc[mi][ni][r] + bv;
                unsigned short hb = f2bf(val);
                Ohi[(size_t)(gr + r) * GK + gc] = hb;
                Olo[(size_t)(gr + r) * GK + gc] = f2bf(val - bf2f(hb));
            }
        }
}

// ------------------------------------------------------------------
// Mixed GEMM, plain bf16 single-MFMA.
// MODE 0 (V^T): A = w_v f32 [1024][1024], B = values f32 [4096][1024],
//               out bf16 C[m][n] (ld 4096), bias per ROW.
// MODE 1 (O):   A = Mb bf16 [4096][1024], B = w_o f32 [1024][1024],
//               out f32 (ld 1024), bias per COL.
// ------------------------------------------------------------------
template<int MODE>
__global__ __launch_bounds__(256)
void gemm_mixed(const void* __restrict__ Ap, const void* __restrict__ Bp,
                const float* __restrict__ bias, void* __restrict__ Op)
{
    __shared__ alignas(16) short Ah[SBM * SLD];
    __shared__ alignas(16) short Bh[SBN * SLD];

    const int tid = threadIdx.x, lane = tid & 63, wv = tid >> 6;
    const int lr = lane & 15, lg = lane >> 4;
    const int m0 = blockIdx.y * SBM, n0 = blockIdx.x * SBN;
    const int wm = (wv >> 1) * 64, wn = (wv & 1) * 32;

    f32x4 acc[4][2] = {};

    for (int k0 = 0; k0 < GK; k0 += 64) {
        if (MODE == 0) {
            const float* A = (const float*)Ap;
            #pragma unroll
            for (int i = 0; i < 8; ++i) {
                int idx = tid + 256 * i, r = idx >> 4, c = idx & 15;
                float4v v = *(const float4v*)(A + (size_t)(m0 + r) * GK + k0 + c * 4);
                short4v h;
                #pragma unroll
                for (int j = 0; j < 4; ++j) h[j] = (short)f2bf(v[j]);
                *(short4v*)(Ah + r * SLD + c * 4) = h;
            }
        } else {
            const ushort_t* A = (const ushort_t*)Ap;
            #pragma unroll
            for (int i = 0; i < 4; ++i) {
                int idx = tid + 256 * i, r = idx >> 3, c = idx & 7;
                *(bf16x8*)(Ah + r * SLD + c * 8) =
                    *(const bf16x8*)(A + (size_t)(m0 + r) * GK + k0 + c * 8);
            }
        }
        {
            const float* B = (const float*)Bp;
            #pragma unroll
            for (int i = 0; i < 4; ++i) {
                int idx = tid + 256 * i, r = idx >> 4, c = idx & 15;
                float4v v = *(const float4v*)(B + (size_t)(n0 + r) * GK + k0 + c * 4);
                short4v h;
                #pragma unroll
                for (int j = 0; j < 4; ++j) h[j] = (short)f2bf(v[j]);
                *(short4v*)(Bh + r * SLD + c * 4) = h;
            }
        }
        __syncthreads();

        #pragma unroll
        for (int ks = 0; ks < 2; ++ks) {
            bf16x8 af[4], bfr[2];
            #pragma unroll
            for (int mi = 0; mi < 4; ++mi)
                af[mi] = *(const bf16x8*)(Ah + (wm + mi * 16 + lr) * SLD + ks * 32 + lg * 8);
            #pragma unroll
            for (int ni = 0; ni < 2; ++ni)
                bfr[ni] = *(const bf16x8*)(Bh + (wn + ni * 16 + lr) * SLD + ks * 32 + lg * 8);
            #pragma unroll
            for (int mi = 0; mi < 4; ++mi)
                #pragma unroll
                for (int ni = 0; ni < 2; ++ni)
                    acc[mi][ni] = mfma16(af[mi], bfr[ni], acc[mi][ni]);
        }
        __syncthreads();
    }

    #pragma unroll
    for (int mi = 0; mi < 4; ++mi)
        #pragma unroll
        for (int ni = 0; ni < 2; ++ni) {
            const int gr = m0 + wm + mi * 16 + lg * 4;
            const int gc = n0 + wn + ni * 16 + lr;
            #pragma unroll
            for (int r = 0; r < 4; ++r) {
                if (MODE == 0) {
                    float val = acc[mi][ni][r] + bias[gr + r];
                    ((ushort_t*)Op)[(size_t)(gr + r) * 4096 + gc] = f2bf(val);
                } else {
                    float val = acc[mi][ni][r] + bias[gc];
                    ((float*)Op)[(size_t)(gr + r) * 1024 + gc] = val;
                }
            }
        }
}

// ------------------------------------------------------------------
// Flash attention, minimal-LDS version.
// Q hi/lo in regs; K hi/lo frags and V^T frags straight from global.
// Per-wave P transpose buffer in LDS (no barriers anywhere).
// QT=64 (16 q-rows/wave), KTILE=128.
// ------------------------------------------------------------------
constexpr int SEQ = 2048, DM = 1024, KT2 = 128, LPP2 = 136;

__global__ __launch_bounds__(256, 4)
void attn2_kernel(const ushort_t* __restrict__ Qhi, const ushort_t* __restrict__ Qlo,
                  const ushort_t* __restrict__ Khi, const ushort_t* __restrict__ Klo,
                  const ushort_t* __restrict__ Vt,  ushort_t* __restrict__ Mrg)
{
    __shared__ alignas(16) short Pl[64 * LPP2];

    const int tid = threadIdx.x, lane = tid & 63, wv = tid >> 6;
    const int lr = lane & 15, lg = lane >> 4;

    // XCD swizzle: co-locate the 32 q-tiles of one (b,h) on one XCD's L2
    const int f = blockIdx.y * 32 + blockIdx.x;          // 0..1023
    const int g = (f & 7) * 128 + (f >> 3);
    const int qt = g & 31, bh = g >> 5;
    const int b = bh >> 4, h = bh & 15;
    const size_t seq0 = (size_t)b * SEQ;
    const int col0 = h * 64;

    // Q fragments (A-operand): row = lr, k = ks*32 + lg*8
    const int qrow = qt * 64 + wv * 16 + lr;
    bf16x8 qh[2], ql[2];
    #pragma unroll
    for (int ks = 0; ks < 2; ++ks) {
        qh[ks] = *(const bf16x8*)(Qhi + (seq0 + qrow) * DM + col0 + ks * 32 + lg * 8);
        ql[ks] = *(const bf16x8*)(Qlo + (seq0 + qrow) * DM + col0 + ks * 32 + lg * 8);
    }

    f32x4 acc_o[4] = {};
    float m_run[4], l_run[4];
    #pragma unroll
    for (int r = 0; r < 4; ++r) { m_run[r] = -1e30f; l_run[r] = 0.f; }

    short* Pw = Pl + wv * 16 * LPP2;

    for (int kt = 0; kt < SEQ; kt += KT2) {
        // ---- scores: S = Q K^T (hi/lo 3-MFMA), K frags from global ----
        f32x4 s[8] = {};
        #pragma unroll
        for (int ks = 0; ks < 2; ++ks)
            #pragma unroll
            for (int ni = 0; ni < 8; ++ni) {
                const size_t off = (seq0 + kt + ni * 16 + lr) * DM + col0 + ks * 32 + lg * 8;
                bf16x8 kh = *(const bf16x8*)(Khi + off);
                bf16x8 kl = *(const bf16x8*)(Klo + off);
                s[ni] = mfma16(qh[ks], kh, s[ni]);
                s[ni] = mfma16(qh[ks], kl, s[ni]);
                s[ni] = mfma16(ql[ks], kh, s[ni]);
            }

        // ---- online softmax (rows q = lg*4+r, cols k = ni*16+lr) ----
        #pragma unroll
        for (int ni = 0; ni < 8; ++ni) s[ni] *= 0.125f;
        #pragma unroll
        for (int r = 0; r < 4; ++r) {
            float mx = s[0][r];
            #pragma unroll
            for (int ni = 1; ni < 8; ++ni) mx = fmaxf(mx, s[ni][r]);
            #pragma unroll
            for (int msk = 1; msk < 16; msk <<= 1) mx = fmaxf(mx, __shfl_xor(mx, msk));
            const float mnew  = fmaxf(m_run[r], mx);
            const float alpha = __expf(m_run[r] - mnew);
            m_run[r] = mnew;
            float rs = 0.f;
            #pragma unroll
            for (int ni = 0; ni < 8; ++ni) {
                float pv = __expf(s[ni][r] - mnew);
                rs += pv;
                Pw[(lg * 4 + r) * LPP2 + ni * 16 + lr] = (short)f2bf(pv);
            }
            #pragma unroll
            for (int msk = 1; msk < 16; msk <<= 1) rs += __shfl_xor(rs, msk);
            l_run[r] = l_run[r] * alpha + rs;
            #pragma unroll
            for (int di = 0; di < 4; ++di) acc_o[di][r] *= alpha;
        }

        // ---- PV: O += P @ V, V^T frags from global ----
        #pragma unroll
        for (int ksv = 0; ksv < 4; ++ksv) {
            bf16x8 pf = *(const bf16x8*)(Pw + lr * LPP2 + ksv * 32 + lg * 8);
            #pragma unroll
            for (int di = 0; di < 4; ++di) {
                bf16x8 vf = *(const bf16x8*)(Vt + (size_t)(col0 + di * 16 + lr) * 4096
                                             + seq0 + kt + ksv * 32 + lg * 8);
                acc_o[di] = mfma16(pf, vf, acc_o[di]);
            }
        }
    }

    // ---- epilogue ----
    #pragma unroll
    for (int di = 0; di < 4; ++di) {
        const int q = qt * 64 + wv * 16 + lg * 4;
        const int d = col0 + di * 16 + lr;
        #pragma unroll
        for (int r = 0; r < 4; ++r) {
            float val = acc_o[di][r] / l_run[r];
            Mrg[(seq0 + q + r) * DM + d] = f2bf(val);
        }
    }
}

// ------------------------------------------------------------------
extern "C" void kernel_launch(void* const* d_in, const int* in_sizes, int n_in,
                              void* d_out, int out_size, void* d_ws, size_t ws_size,
                              hipStream_t stream)
{
    const float* queries = (const float*)d_in[0];
    const float* keys    = (const float*)d_in[1];
    const float* values  = (const float*)d_in[2];
    const float* w_q = (const float*)d_in[3];
    const float* b_q = (const float*)d_in[4];
    const float* w_k = (const float*)d_in[5];
    const float* b_k = (const float*)d_in[6];
    const float* w_v = (const float*)d_in[7];
    const float* b_v = (const float*)d_in[8];
    const float* w_o = (const float*)d_in[9];
    const float* b_o = (const float*)d_in[10];

    const size_t MB = 1u << 20;
    char* ws = (char*)d_ws;
    // [0,16)  queries hi/lo  -> later Khi/Klo (K-proj output)
    // [16,32) Qhi/Qlo        (Q-proj output)
    // [32,40) Vt             (V^T, bf16 [1024][4096])
    // [40,48) Mb (attn out); first 4 MB doubles as weight-split scratch
    ushort_t* q_hi   = (ushort_t*)(ws);
    ushort_t* q_lo   = (ushort_t*)(ws + 8 * MB);
    ushort_t* Khi    = (ushort_t*)(ws);
    ushort_t* Klo    = (ushort_t*)(ws + 8 * MB);
    ushort_t* Qhi    = (ushort_t*)(ws + 16 * MB);
    ushort_t* Qlo    = (ushort_t*)(ws + 24 * MB);
    ushort_t* Vt     = (ushort_t*)(ws + 32 * MB);
    ushort_t* Mb     = (ushort_t*)(ws + 40 * MB);
    ushort_t* wsp_hi = (ushort_t*)(ws + 40 * MB);
    ushort_t* wsp_lo = (ushort_t*)(ws + 42 * MB);
    ushort_t* k_hi   = (ushort_t*)d_out;                    // keys split lives in d_out
    ushort_t* k_lo   = (ushort_t*)((char*)d_out + 8 * MB);  // (dead before O-proj writes)

    const int n4_act = 4096 * 1024 / 4, n4_w = 1024 * 1024 / 4;
    dim3 blk(256);

    hipLaunchKernelGGL(split_kernel, dim3(2048), blk, 0, stream, queries, q_hi, q_lo, n4_act);
    hipLaunchKernelGGL(split_kernel, dim3(2048), blk, 0, stream, keys, k_hi, k_lo, n4_act);
    hipLaunchKernelGGL(split_kernel, dim3(1024), blk, 0, stream, w_q, wsp_hi, wsp_lo, n4_w);
    hipLaunchKernelGGL(gemm_split, dim3(16, 32), blk, 0, stream,
                       q_hi, q_lo, wsp_hi, wsp_lo, b_q, Qhi, Qlo);
    hipLaunchKernelGGL(split_kernel, dim3(1024), blk, 0, stream, w_k, wsp_hi, wsp_lo, n4_w);
    hipLaunchKernelGGL(gemm_split, dim3(16, 32), blk, 0, stream,
                       k_hi, k_lo, wsp_hi, wsp_lo, b_k, Khi, Klo);
    hipLaunchKernelGGL((gemm_mixed<0>), dim3(64, 8), blk, 0, stream, w_v, values, b_v, Vt);
    hipLaunchKernelGGL(attn2_kernel, dim3(32, 32), blk, 0, stream, Qhi, Qlo, Khi, Klo, Vt, Mb);
    hipLaunchKernelGGL((gemm_mixed<1>), dim3(16, 32), blk, 0, stream, Mb, w_o, b_o, (float*)d_out);
}

// Round 3
// 284.440 us; speedup vs baseline: 2.0552x; 1.6987x over previous
//
#include <hip/hip_runtime.h>

typedef __attribute__((ext_vector_type(8))) short bf16x8;
typedef __attribute__((ext_vector_type(4))) short short4v;
typedef __attribute__((ext_vector_type(4))) float f32x4;
typedef __attribute__((ext_vector_type(4))) float float4v;
typedef unsigned short ushort_t;

__device__ __forceinline__ unsigned short f2bf(float x) {
    unsigned u = __float_as_uint(x);
    return (unsigned short)((u + 0x7fffu + ((u >> 16) & 1u)) >> 16);
}
__device__ __forceinline__ float bf2f(unsigned short b) {
    return __uint_as_float(((unsigned)b) << 16);
}
__device__ __forceinline__ f32x4 mfma16(bf16x8 a, bf16x8 b, f32x4 c) {
    return __builtin_amdgcn_mfma_f32_16x16x32_bf16(a, b, c, 0, 0, 0);
}

constexpr int GK = 1024;   // K-dim of every GEMM

// ------------------------------------------------------------------
// Elementwise split: f32 -> (hi, lo) bf16 arrays. n4 = N/4.
// ------------------------------------------------------------------
__global__ __launch_bounds__(256)
void split_kernel(const float* __restrict__ in, ushort_t* __restrict__ hi,
                  ushort_t* __restrict__ lo, int n4)
{
    int i = blockIdx.x * blockDim.x + threadIdx.x;
    const int stride = gridDim.x * blockDim.x;
    for (; i < n4; i += stride) {
        float4v v = ((const float4v*)in)[i];
        short4v h, l;
        #pragma unroll
        for (int j = 0; j < 4; ++j) {
            unsigned short hb = f2bf(v[j]);
            h[j] = (short)hb;
            l[j] = (short)f2bf(v[j] - bf2f(hb));
        }
        ((short4v*)hi)[i] = h;
        ((short4v*)lo)[i] = l;
    }
}

// ------------------------------------------------------------------
// Split GEMM (Q/K projections): all inputs pre-split bf16.
// Y = X @ W^T + bias, 3-MFMA hi/lo, output written as hi/lo bf16.
// M=4096, N=K=1024. BM=128, BN=64, BK=64, 256 thr (4 waves).
// ------------------------------------------------------------------
constexpr int SBM = 128, SBN = 64, SLD = 72;  // 72 shorts = 144 B row stride

__global__ __launch_bounds__(256)
void gemm_split(const ushort_t* __restrict__ Ahi, const ushort_t* __restrict__ Alo,
                const ushort_t* __restrict__ Bhi, const ushort_t* __restrict__ Blo,
                const float* __restrict__ bias,
                ushort_t* __restrict__ Ohi, ushort_t* __restrict__ Olo)
{
    __shared__ alignas(16) short Ah[SBM * SLD], Al[SBM * SLD];
    __shared__ alignas(16) short Bh[SBN * SLD], Bl[SBN * SLD];

    const int tid = threadIdx.x, lane = tid & 63, wv = tid >> 6;
    const int lr = lane & 15, lg = lane >> 4;
    const int m0 = blockIdx.y * SBM, n0 = blockIdx.x * SBN;
    const int wm = (wv >> 1) * 64, wn = (wv & 1) * 32;

    f32x4 acc[4][2] = {};

    for (int k0 = 0; k0 < GK; k0 += 64) {
        #pragma unroll
        for (int i = 0; i < 4; ++i) {
            int idx = tid + 256 * i, r = idx >> 3, c = idx & 7;
            *(bf16x8*)(Ah + r * SLD + c * 8) =
                *(const bf16x8*)(Ahi + (size_t)(m0 + r) * GK + k0 + c * 8);
            *(bf16x8*)(Al + r * SLD + c * 8) =
                *(const bf16x8*)(Alo + (size_t)(m0 + r) * GK + k0 + c * 8);
        }
        #pragma unroll
        for (int i = 0; i < 2; ++i) {
            int idx = tid + 256 * i, r = idx >> 3, c = idx & 7;
            *(bf16x8*)(Bh + r * SLD + c * 8) =
                *(const bf16x8*)(Bhi + (size_t)(n0 + r) * GK + k0 + c * 8);
            *(bf16x8*)(Bl + r * SLD + c * 8) =
                *(const bf16x8*)(Blo + (size_t)(n0 + r) * GK + k0 + c * 8);
        }
        __syncthreads();

        #pragma unroll
        for (int ks = 0; ks < 2; ++ks) {
            bf16x8 af[4], afl[4], bfr[2], bfl[2];
            #pragma unroll
            for (int mi = 0; mi < 4; ++mi) {
                const int row = wm + mi * 16 + lr;
                af[mi]  = *(const bf16x8*)(Ah + row * SLD + ks * 32 + lg * 8);
                afl[mi] = *(const bf16x8*)(Al + row * SLD + ks * 32 + lg * 8);
            }
            #pragma unroll
            for (int ni = 0; ni < 2; ++ni) {
                const int row = wn + ni * 16 + lr;
                bfr[ni] = *(const bf16x8*)(Bh + row * SLD + ks * 32 + lg * 8);
                bfl[ni] = *(const bf16x8*)(Bl + row * SLD + ks * 32 + lg * 8);
            }
            #pragma unroll
            for (int mi = 0; mi < 4; ++mi)
                #pragma unroll
                for (int ni = 0; ni < 2; ++ni) {
                    acc[mi][ni] = mfma16(af[mi],  bfr[ni], acc[mi][ni]);
                    acc[mi][ni] = mfma16(af[mi],  bfl[ni], acc[mi][ni]);
                    acc[mi][ni] = mfma16(afl[mi], bfr[ni], acc[mi][ni]);
                }
        }
        __syncthreads();
    }

    #pragma unroll
    for (int mi = 0; mi < 4; ++mi)
        #pragma unroll
        for (int ni = 0; ni < 2; ++ni) {
            const int gr = m0 + wm + mi * 16 + lg * 4;
            const int gc = n0 + wn + ni * 16 + lr;
            const float bv = bias[gc];
            #pragma unroll
            for (int r = 0; r < 4; ++r) {
                float val = acc[mi][ni][r] + bv;
                unsigned short hb = f2bf(val);
                Ohi[(size_t)(gr + r) * GK + gc] = hb;
                Olo[(size_t)(gr + r) * GK + gc] = f2bf(val - bf2f(hb));
            }
        }
}

// ------------------------------------------------------------------
// Mixed GEMM, plain bf16 single-MFMA.
// MODE 0 (V^T): A = w_v f32 [1024][1024], B = values f32 [4096][1024],
//               out bf16 C[m][n] (ld 4096), bias per ROW.
// MODE 1 (O):   A = Mb bf16 [4096][1024], B = w_o f32 [1024][1024],
//               out f32 (ld 1024), bias per COL.
// ------------------------------------------------------------------
template<int MODE>
__global__ __launch_bounds__(256)
void gemm_mixed(const void* __restrict__ Ap, const void* __restrict__ Bp,
                const float* __restrict__ bias, void* __restrict__ Op)
{
    __shared__ alignas(16) short Ah[SBM * SLD];
    __shared__ alignas(16) short Bh[SBN * SLD];

    const int tid = threadIdx.x, lane = tid & 63, wv = tid >> 6;
    const int lr = lane & 15, lg = lane >> 4;
    const int m0 = blockIdx.y * SBM, n0 = blockIdx.x * SBN;
    const int wm = (wv >> 1) * 64, wn = (wv & 1) * 32;

    f32x4 acc[4][2] = {};

    for (int k0 = 0; k0 < GK; k0 += 64) {
        if (MODE == 0) {
            const float* A = (const float*)Ap;
            #pragma unroll
            for (int i = 0; i < 8; ++i) {
                int idx = tid + 256 * i, r = idx >> 4, c = idx & 15;
                float4v v = *(const float4v*)(A + (size_t)(m0 + r) * GK + k0 + c * 4);
                short4v h;
                #pragma unroll
                for (int j = 0; j < 4; ++j) h[j] = (short)f2bf(v[j]);
                *(short4v*)(Ah + r * SLD + c * 4) = h;
            }
        } else {
            const ushort_t* A = (const ushort_t*)Ap;
            #pragma unroll
            for (int i = 0; i < 4; ++i) {
                int idx = tid + 256 * i, r = idx >> 3, c = idx & 7;
                *(bf16x8*)(Ah + r * SLD + c * 8) =
                    *(const bf16x8*)(A + (size_t)(m0 + r) * GK + k0 + c * 8);
            }
        }
        {
            const float* B = (const float*)Bp;
            #pragma unroll
            for (int i = 0; i < 4; ++i) {
                int idx = tid + 256 * i, r = idx >> 4, c = idx & 15;
                float4v v = *(const float4v*)(B + (size_t)(n0 + r) * GK + k0 + c * 4);
                short4v h;
                #pragma unroll
                for (int j = 0; j < 4; ++j) h[j] = (short)f2bf(v[j]);
                *(short4v*)(Bh + r * SLD + c * 4) = h;
            }
        }
        __syncthreads();

        #pragma unroll
        for (int ks = 0; ks < 2; ++ks) {
            bf16x8 af[4], bfr[2];
            #pragma unroll
            for (int mi = 0; mi < 4; ++mi)
                af[mi] = *(const bf16x8*)(Ah + (wm + mi * 16 + lr) * SLD + ks * 32 + lg * 8);
            #pragma unroll
            for (int ni = 0; ni < 2; ++ni)
                bfr[ni] = *(const bf16x8*)(Bh + (wn + ni * 16 + lr) * SLD + ks * 32 + lg * 8);
            #pragma unroll
            for (int mi = 0; mi < 4; ++mi)
                #pragma unroll
                for (int ni = 0; ni < 2; ++ni)
                    acc[mi][ni] = mfma16(af[mi], bfr[ni], acc[mi][ni]);
        }
        __syncthreads();
    }

    #pragma unroll
    for (int mi = 0; mi < 4; ++mi)
        #pragma unroll
        for (int ni = 0; ni < 2; ++ni) {
            const int gr = m0 + wm + mi * 16 + lg * 4;
            const int gc = n0 + wn + ni * 16 + lr;
            #pragma unroll
            for (int r = 0; r < 4; ++r) {
                if (MODE == 0) {
                    float val = acc[mi][ni][r] + bias[gr + r];
                    ((ushort_t*)Op)[(size_t)(gr + r) * 4096 + gc] = f2bf(val);
                } else {
                    float val = acc[mi][ni][r] + bias[gc];
                    ((float*)Op)[(size_t)(gr + r) * 1024 + gc] = val;
                }
            }
        }
}

// ------------------------------------------------------------------
// Flash attention v3: cooperative LDS staging + 1-deep pipeline.
// QT=128 (4 waves x 32 q-rows), KT=64.
// LDS: Kh/Kl/Vs 64x72 each (+pad) staged per tile; Ps 128x76 per-wave P.
// Pipeline per tile: barrier -> ds_write(regs) -> barrier ->
//                    issue global loads (t+1) -> compute (QK^T/softmax/PV).
// ------------------------------------------------------------------
constexpr int SEQ = 2048, DM = 1024;
constexpr int AKT = 64, ALD = 72, PLD = 76;

__global__ __launch_bounds__(256, 3)
void attn3_kernel(const ushort_t* __restrict__ Qhi, const ushort_t* __restrict__ Qlo,
                  const ushort_t* __restrict__ Khi, const ushort_t* __restrict__ Klo,
                  const ushort_t* __restrict__ Vt,  ushort_t* __restrict__ Mrg)
{
    __shared__ alignas(16) short Kh[AKT * ALD];
    __shared__ alignas(16) short Kl[AKT * ALD];
    __shared__ alignas(16) short Vs[AKT * ALD];
    __shared__ alignas(16) short Ps[128 * PLD];

    const int tid = threadIdx.x, lane = tid & 63, wv = tid >> 6;
    const int lr = lane & 15, lg = lane >> 4;

    // bijective XCD swizzle: each XCD gets 4 complete (b,h) groups
    const int f = blockIdx.y * 16 + blockIdx.x;   // 0..511
    const int g = (f & 7) * 64 + (f >> 3);
    const int qt = g & 15, bh = g >> 4;
    const int b = bh >> 4, h = bh & 15;
    const size_t seq0 = (size_t)b * SEQ;
    const int col0 = h * 64;

    // Q fragments (A-operand, 32 rows/wave): row = mi*16+lr, k = ks*32+lg*8
    bf16x8 qh[2][2], ql[2][2];
    #pragma unroll
    for (int mi = 0; mi < 2; ++mi)
        #pragma unroll
        for (int ks = 0; ks < 2; ++ks) {
            const size_t off = (seq0 + qt * 128 + wv * 32 + mi * 16 + lr) * DM
                             + col0 + ks * 32 + lg * 8;
            qh[mi][ks] = *(const bf16x8*)(Qhi + off);
            ql[mi][ks] = *(const bf16x8*)(Qlo + off);
        }

    f32x4 acc_o[2][4] = {};
    float m_run[2][4], l_run[2][4];
    #pragma unroll
    for (int mi = 0; mi < 2; ++mi)
        #pragma unroll
        for (int r = 0; r < 4; ++r) { m_run[mi][r] = -1e30f; l_run[mi][r] = 0.f; }

    short* Pw = Ps + wv * 32 * PLD;

    // staging indices: chunk p covers rows (tid>>3)+32p, col (tid&7)*8
    const int sr = tid >> 3, sc = tid & 7;

    // prologue: load tile 0
    bf16x8 gkh[2], gkl[2], gvv[2];
    #pragma unroll
    for (int p = 0; p < 2; ++p) {
        const size_t koff = (seq0 + sr + 32 * p) * DM + col0 + sc * 8;
        gkh[p] = *(const bf16x8*)(Khi + koff);
        gkl[p] = *(const bf16x8*)(Klo + koff);
        gvv[p] = *(const bf16x8*)(Vt + (size_t)(col0 + sr + 32 * p) * 4096 + seq0 + sc * 8);
    }

    for (int kt = 0; kt < SEQ; kt += AKT) {
        __syncthreads();   // previous tile's compute done reading LDS
        #pragma unroll
        for (int p = 0; p < 2; ++p) {
            *(bf16x8*)(Kh + (sr + 32 * p) * ALD + sc * 8) = gkh[p];
            *(bf16x8*)(Kl + (sr + 32 * p) * ALD + sc * 8) = gkl[p];
            *(bf16x8*)(Vs + (sr + 32 * p) * ALD + sc * 8) = gvv[p];
        }
        __syncthreads();   // tile ready

        // issue next tile's loads (hide under compute)
        {
            const int ktn = (kt + AKT < SEQ) ? kt + AKT : kt;
            #pragma unroll
            for (int p = 0; p < 2; ++p) {
                const size_t koff = (seq0 + ktn + sr + 32 * p) * DM + col0 + sc * 8;
                gkh[p] = *(const bf16x8*)(Khi + koff);
                gkl[p] = *(const bf16x8*)(Klo + koff);
                gvv[p] = *(const bf16x8*)(Vt + (size_t)(col0 + sr + 32 * p) * 4096
                                          + seq0 + ktn + sc * 8);
            }
        }

        // ---- QK^T: hi/lo 3-MFMA ----
        f32x4 s[2][4] = {};
        #pragma unroll
        for (int ks = 0; ks < 2; ++ks) {
            bf16x8 khf[4], klf[4];
            #pragma unroll
            for (int ni = 0; ni < 4; ++ni) {
                const int off = (ni * 16 + lr) * ALD + ks * 32 + lg * 8;
                khf[ni] = *(const bf16x8*)(Kh + off);
                klf[ni] = *(const bf16x8*)(Kl + off);
            }
            #pragma unroll
            for (int mi = 0; mi < 2; ++mi)
                #pragma unroll
                for (int ni = 0; ni < 4; ++ni) {
                    s[mi][ni] = mfma16(qh[mi][ks], khf[ni], s[mi][ni]);
                    s[mi][ni] = mfma16(qh[mi][ks], klf[ni], s[mi][ni]);
                    s[mi][ni] = mfma16(ql[mi][ks], khf[ni], s[mi][ni]);
                }
        }

        // ---- online softmax (rows q = mi*16+lg*4+r, cols k = ni*16+lr) ----
        #pragma unroll
        for (int mi = 0; mi < 2; ++mi) {
            #pragma unroll
            for (int ni = 0; ni < 4; ++ni) s[mi][ni] *= 0.125f;
            #pragma unroll
            for (int r = 0; r < 4; ++r) {
                float mx = fmaxf(fmaxf(s[mi][0][r], s[mi][1][r]),
                                 fmaxf(s[mi][2][r], s[mi][3][r]));
                #pragma unroll
                for (int msk = 1; msk < 16; msk <<= 1) mx = fmaxf(mx, __shfl_xor(mx, msk));
                const float mnew  = fmaxf(m_run[mi][r], mx);
                const float alpha = __expf(m_run[mi][r] - mnew);
                m_run[mi][r] = mnew;
                float rs = 0.f;
                #pragma unroll
                for (int ni = 0; ni < 4; ++ni) {
                    float pv = __expf(s[mi][ni][r] - mnew);
                    rs += pv;
                    Pw[(mi * 16 + lg * 4 + r) * PLD + ni * 16 + lr] = (short)f2bf(pv);
                }
                #pragma unroll
                for (int msk = 1; msk < 16; msk <<= 1) rs += __shfl_xor(rs, msk);
                l_run[mi][r] = l_run[mi][r] * alpha + rs;
                #pragma unroll
                for (int di = 0; di < 4; ++di) acc_o[mi][di][r] *= alpha;
            }
        }

        // ---- PV: O += P @ V ----
        #pragma unroll
        for (int ksv = 0; ksv < 2; ++ksv) {
            bf16x8 pf[2];
            #pragma unroll
            for (int mi = 0; mi < 2; ++mi)
                pf[mi] = *(const bf16x8*)(Pw + (mi * 16 + lr) * PLD + ksv * 32 + lg * 8);
            #pragma unroll
            for (int di = 0; di < 4; ++di) {
                bf16x8 vf = *(const bf16x8*)(Vs + (di * 16 + lr) * ALD + ksv * 32 + lg * 8);
                #pragma unroll
                for (int mi = 0; mi < 2; ++mi)
                    acc_o[mi][di] = mfma16(pf[mi], vf, acc_o[mi][di]);
            }
        }
    }

    // ---- epilogue ----
    #pragma unroll
    for (int mi = 0; mi < 2; ++mi)
        #pragma unroll
        for (int di = 0; di < 4; ++di) {
            const int q = qt * 128 + wv * 32 + mi * 16 + lg * 4;
            const int d = col0 + di * 16 + lr;
            #pragma unroll
            for (int r = 0; r < 4; ++r) {
                float val = acc_o[mi][di][r] / l_run[mi][r];
                Mrg[(seq0 + q + r) * DM + d] = f2bf(val);
            }
        }
}

// ------------------------------------------------------------------
extern "C" void kernel_launch(void* const* d_in, const int* in_sizes, int n_in,
                              void* d_out, int out_size, void* d_ws, size_t ws_size,
                              hipStream_t stream)
{
    const float* queries = (const float*)d_in[0];
    const float* keys    = (const float*)d_in[1];
    const float* values  = (const float*)d_in[2];
    const float* w_q = (const float*)d_in[3];
    const float* b_q = (const float*)d_in[4];
    const float* w_k = (const float*)d_in[5];
    const float* b_k = (const float*)d_in[6];
    const float* w_v = (const float*)d_in[7];
    const float* b_v = (const float*)d_in[8];
    const float* w_o = (const float*)d_in[9];
    const float* b_o = (const float*)d_in[10];

    const size_t MB = 1u << 20;
    char* ws = (char*)d_ws;
    ushort_t* q_hi   = (ushort_t*)(ws);
    ushort_t* q_lo   = (ushort_t*)(ws + 8 * MB);
    ushort_t* Khi    = (ushort_t*)(ws);
    ushort_t* Klo    = (ushort_t*)(ws + 8 * MB);
    ushort_t* Qhi    = (ushort_t*)(ws + 16 * MB);
    ushort_t* Qlo    = (ushort_t*)(ws + 24 * MB);
    ushort_t* Vt     = (ushort_t*)(ws + 32 * MB);
    ushort_t* Mb     = (ushort_t*)(ws + 40 * MB);
    ushort_t* wsp_hi = (ushort_t*)(ws + 40 * MB);
    ushort_t* wsp_lo = (ushort_t*)(ws + 42 * MB);
    ushort_t* k_hi   = (ushort_t*)d_out;                    // keys split lives in d_out
    ushort_t* k_lo   = (ushort_t*)((char*)d_out + 8 * MB);  // (dead before O-proj writes)

    const int n4_act = 4096 * 1024 / 4, n4_w = 1024 * 1024 / 4;
    dim3 blk(256);

    hipLaunchKernelGGL(split_kernel, dim3(2048), blk, 0, stream, queries, q_hi, q_lo, n4_act);
    hipLaunchKernelGGL(split_kernel, dim3(2048), blk, 0, stream, keys, k_hi, k_lo, n4_act);
    hipLaunchKernelGGL(split_kernel, dim3(1024), blk, 0, stream, w_q, wsp_hi, wsp_lo, n4_w);
    hipLaunchKernelGGL(gemm_split, dim3(16, 32), blk, 0, stream,
                       q_hi, q_lo, wsp_hi, wsp_lo, b_q, Qhi, Qlo);
    hipLaunchKernelGGL(split_kernel, dim3(1024), blk, 0, stream, w_k, wsp_hi, wsp_lo, n4_w);
    hipLaunchKernelGGL(gemm_split, dim3(16, 32), blk, 0, stream,
                       k_hi, k_lo, wsp_hi, wsp_lo, b_k, Khi, Klo);
    hipLaunchKernelGGL((gemm_mixed<0>), dim3(64, 8), blk, 0, stream, w_v, values, b_v, Vt);
    hipLaunchKernelGGL(attn3_kernel, dim3(16, 32), blk, 0, stream, Qhi, Qlo, Khi, Klo, Vt, Mb);
    hipLaunchKernelGGL((gemm_mixed<1>), dim3(16, 32), blk, 0, stream, Mb, w_o, b_o, (float*)d_out);
}

// Round 4
// 220.609 us; speedup vs baseline: 2.6499x; 1.2893x over previous
//
#include <hip/hip_runtime.h>

typedef __attribute__((ext_vector_type(8))) short bf16x8;
typedef __attribute__((ext_vector_type(4))) short short4v;
typedef __attribute__((ext_vector_type(4))) float f32x4;
typedef __attribute__((ext_vector_type(16))) float f32x16;
typedef __attribute__((ext_vector_type(4))) float float4v;
typedef unsigned short ushort_t;

__device__ __forceinline__ unsigned short f2bf(float x) {
    unsigned u = __float_as_uint(x);
    return (unsigned short)((u + 0x7fffu + ((u >> 16) & 1u)) >> 16);
}
__device__ __forceinline__ float bf2f(unsigned short b) {
    return __uint_as_float(((unsigned)b) << 16);
}
__device__ __forceinline__ f32x4 mfma16(bf16x8 a, bf16x8 b, f32x4 c) {
    return __builtin_amdgcn_mfma_f32_16x16x32_bf16(a, b, c, 0, 0, 0);
}
__device__ __forceinline__ f32x16 mfma32(bf16x8 a, bf16x8 b, f32x16 c) {
    return __builtin_amdgcn_mfma_f32_32x32x16_bf16(a, b, c, 0, 0, 0);
}
__device__ __forceinline__ unsigned cvtpk(float lo, float hi) {
    unsigned r;
    asm("v_cvt_pk_bf16_f32 %0, %1, %2" : "=v"(r) : "v"(lo), "v"(hi));
    return r;
}
__device__ __forceinline__ bf16x8 pack4(unsigned w0, unsigned w1, unsigned w2, unsigned w3) {
    union { unsigned u[4]; bf16x8 v; } c;
    c.u[0] = w0; c.u[1] = w1; c.u[2] = w2; c.u[3] = w3;
    return c.v;
}

constexpr int GK = 1024;   // K-dim of every GEMM

// ------------------------------------------------------------------
// Elementwise split: f32 -> (hi, lo) bf16 arrays. n4 = N/4.
// ------------------------------------------------------------------
__global__ __launch_bounds__(256)
void split_kernel(const float* __restrict__ in, ushort_t* __restrict__ hi,
                  ushort_t* __restrict__ lo, int n4)
{
    int i = blockIdx.x * blockDim.x + threadIdx.x;
    const int stride = gridDim.x * blockDim.x;
    for (; i < n4; i += stride) {
        float4v v = ((const float4v*)in)[i];
        short4v h, l;
        #pragma unroll
        for (int j = 0; j < 4; ++j) {
            unsigned short hb = f2bf(v[j]);
            h[j] = (short)hb;
            l[j] = (short)f2bf(v[j] - bf2f(hb));
        }
        ((short4v*)hi)[i] = h;
        ((short4v*)lo)[i] = l;
    }
}

// ------------------------------------------------------------------
// Split GEMM (Q/K projections): all inputs pre-split bf16.
// ------------------------------------------------------------------
constexpr int SBM = 128, SBN = 64, SLD = 72;

__global__ __launch_bounds__(256)
void gemm_split(const ushort_t* __restrict__ Ahi, const ushort_t* __restrict__ Alo,
                const ushort_t* __restrict__ Bhi, const ushort_t* __restrict__ Blo,
                const float* __restrict__ bias,
                ushort_t* __restrict__ Ohi, ushort_t* __restrict__ Olo)
{
    __shared__ alignas(16) short Ah[SBM * SLD], Al[SBM * SLD];
    __shared__ alignas(16) short Bh[SBN * SLD], Bl[SBN * SLD];

    const int tid = threadIdx.x, lane = tid & 63, wv = tid >> 6;
    const int lr = lane & 15, lg = lane >> 4;
    const int m0 = blockIdx.y * SBM, n0 = blockIdx.x * SBN;
    const int wm = (wv >> 1) * 64, wn = (wv & 1) * 32;

    f32x4 acc[4][2] = {};

    for (int k0 = 0; k0 < GK; k0 += 64) {
        #pragma unroll
        for (int i = 0; i < 4; ++i) {
            int idx = tid + 256 * i, r = idx >> 3, c = idx & 7;
            *(bf16x8*)(Ah + r * SLD + c * 8) =
                *(const bf16x8*)(Ahi + (size_t)(m0 + r) * GK + k0 + c * 8);
            *(bf16x8*)(Al + r * SLD + c * 8) =
                *(const bf16x8*)(Alo + (size_t)(m0 + r) * GK + k0 + c * 8);
        }
        #pragma unroll
        for (int i = 0; i < 2; ++i) {
            int idx = tid + 256 * i, r = idx >> 3, c = idx & 7;
            *(bf16x8*)(Bh + r * SLD + c * 8) =
                *(const bf16x8*)(Bhi + (size_t)(n0 + r) * GK + k0 + c * 8);
            *(bf16x8*)(Bl + r * SLD + c * 8) =
                *(const bf16x8*)(Blo + (size_t)(n0 + r) * GK + k0 + c * 8);
        }
        __syncthreads();

        #pragma unroll
        for (int ks = 0; ks < 2; ++ks) {
            bf16x8 af[4], afl[4], bfr[2], bfl[2];
            #pragma unroll
            for (int mi = 0; mi < 4; ++mi) {
                const int row = wm + mi * 16 + lr;
                af[mi]  = *(const bf16x8*)(Ah + row * SLD + ks * 32 + lg * 8);
                afl[mi] = *(const bf16x8*)(Al + row * SLD + ks * 32 + lg * 8);
            }
            #pragma unroll
            for (int ni = 0; ni < 2; ++ni) {
                const int row = wn + ni * 16 + lr;
                bfr[ni] = *(const bf16x8*)(Bh + row * SLD + ks * 32 + lg * 8);
                bfl[ni] = *(const bf16x8*)(Bl + row * SLD + ks * 32 + lg * 8);
            }
            #pragma unroll
            for (int mi = 0; mi < 4; ++mi)
                #pragma unroll
                for (int ni = 0; ni < 2; ++ni) {
                    acc[mi][ni] = mfma16(af[mi],  bfr[ni], acc[mi][ni]);
                    acc[mi][ni] = mfma16(af[mi],  bfl[ni], acc[mi][ni]);
                    acc[mi][ni] = mfma16(afl[mi], bfr[ni], acc[mi][ni]);
                }
        }
        __syncthreads();
    }

    #pragma unroll
    for (int mi = 0; mi < 4; ++mi)
        #pragma unroll
        for (int ni = 0; ni < 2; ++ni) {
            const int gr = m0 + wm + mi * 16 + lg * 4;
            const int gc = n0 + wn + ni * 16 + lr;
            const float bv = bias[gc];
            #pragma unroll
            for (int r = 0; r < 4; ++r) {
                float val = acc[mi][ni][r] + bv;
                unsigned short hb = f2bf(val);
                Ohi[(size_t)(gr + r) * GK + gc] = hb;
                Olo[(size_t)(gr + r) * GK + gc] = f2bf(val - bf2f(hb));
            }
        }
}

// ------------------------------------------------------------------
// Mixed GEMM, plain bf16 single-MFMA.  (same as round 3)
// ------------------------------------------------------------------
template<int MODE>
__global__ __launch_bounds__(256)
void gemm_mixed(const void* __restrict__ Ap, const void* __restrict__ Bp,
                const float* __restrict__ bias, void* __restrict__ Op)
{
    __shared__ alignas(16) short Ah[SBM * SLD];
    __shared__ alignas(16) short Bh[SBN * SLD];

    const int tid = threadIdx.x, lane = tid & 63, wv = tid >> 6;
    const int lr = lane & 15, lg = lane >> 4;
    const int m0 = blockIdx.y * SBM, n0 = blockIdx.x * SBN;
    const int wm = (wv >> 1) * 64, wn = (wv & 1) * 32;

    f32x4 acc[4][2] = {};

    for (int k0 = 0; k0 < GK; k0 += 64) {
        if (MODE == 0) {
            const float* A = (const float*)Ap;
            #pragma unroll
            for (int i = 0; i < 8; ++i) {
                int idx = tid + 256 * i, r = idx >> 4, c = idx & 15;
                float4v v = *(const float4v*)(A + (size_t)(m0 + r) * GK + k0 + c * 4);
                short4v h;
                #pragma unroll
                for (int j = 0; j < 4; ++j) h[j] = (short)f2bf(v[j]);
                *(short4v*)(Ah + r * SLD + c * 4) = h;
            }
        } else {
            const ushort_t* A = (const ushort_t*)Ap;
            #pragma unroll
            for (int i = 0; i < 4; ++i) {
                int idx = tid + 256 * i, r = idx >> 3, c = idx & 7;
                *(bf16x8*)(Ah + r * SLD + c * 8) =
                    *(const bf16x8*)(A + (size_t)(m0 + r) * GK + k0 + c * 8);
            }
        }
        {
            const float* B = (const float*)Bp;
            #pragma unroll
            for (int i = 0; i < 4; ++i) {
                int idx = tid + 256 * i, r = idx >> 4, c = idx & 15;
                float4v v = *(const float4v*)(B + (size_t)(n0 + r) * GK + k0 + c * 4);
                short4v h;
                #pragma unroll
                for (int j = 0; j < 4; ++j) h[j] = (short)f2bf(v[j]);
                *(short4v*)(Bh + r * SLD + c * 4) = h;
            }
        }
        __syncthreads();

        #pragma unroll
        for (int ks = 0; ks < 2; ++ks) {
            bf16x8 af[4], bfr[2];
            #pragma unroll
            for (int mi = 0; mi < 4; ++mi)
                af[mi] = *(const bf16x8*)(Ah + (wm + mi * 16 + lr) * SLD + ks * 32 + lg * 8);
            #pragma unroll
            for (int ni = 0; ni < 2; ++ni)
                bfr[ni] = *(const bf16x8*)(Bh + (wn + ni * 16 + lr) * SLD + ks * 32 + lg * 8);
            #pragma unroll
            for (int mi = 0; mi < 4; ++mi)
                #pragma unroll
                for (int ni = 0; ni < 2; ++ni)
                    acc[mi][ni] = mfma16(af[mi], bfr[ni], acc[mi][ni]);
        }
        __syncthreads();
    }

    #pragma unroll
    for (int mi = 0; mi < 4; ++mi)
        #pragma unroll
        for (int ni = 0; ni < 2; ++ni) {
            const int gr = m0 + wm + mi * 16 + lg * 4;
            const int gc = n0 + wn + ni * 16 + lr;
            #pragma unroll
            for (int r = 0; r < 4; ++r) {
                if (MODE == 0) {
                    float val = acc[mi][ni][r] + bias[gr + r];
                    ((ushort_t*)Op)[(size_t)(gr + r) * 4096 + gc] = f2bf(val);
                } else {
                    float val = acc[mi][ni][r] + bias[gc];
                    ((float*)Op)[(size_t)(gr + r) * 1024 + gc] = val;
                }
            }
        }
}

// ------------------------------------------------------------------
// Flash attention v4: swapped QK^T 32x32 MFMA, in-register softmax,
// P->PV fragments via cvt_pk + shfl_xor(32) (no P LDS, no 16-lane shfls).
//
// S^T = mfma32(A=K[key][k], B=Q[q][k]) : C col = q = lane&31,
//   row = key = (reg&3)+8*(reg>>2)+4*lg2 (+32 per acc block).
// O^T = mfma32(A=V^T[d][key], B=P[q][key]) : same q-mapping -> alpha
//   rescale is per-lane uniform; l kept lane-partial, combined at end.
// K/V staged in LDS [64][64] shorts with XOR swizzle col8^((row&7)<<3).
// ------------------------------------------------------------------
constexpr int SEQ = 2048, DM = 1024;

__device__ __forceinline__ bf16x8 lds_rd(const short* base, int row, int chunk) {
    return *(const bf16x8*)(base + row * 64 + ((chunk * 8) ^ ((row & 7) << 3)));
}

__global__ __launch_bounds__(256, 3)
void attn4_kernel(const ushort_t* __restrict__ Qhi, const ushort_t* __restrict__ Qlo,
                  const ushort_t* __restrict__ Khi, const ushort_t* __restrict__ Klo,
                  const ushort_t* __restrict__ Vt,  ushort_t* __restrict__ Mrg)
{
    __shared__ alignas(16) short Ksh[64 * 64];
    __shared__ alignas(16) short Ksl[64 * 64];
    __shared__ alignas(16) short Vsm[64 * 64];

    const int tid = threadIdx.x, lane = tid & 63, wv = tid >> 6;
    const int l31 = lane & 31, lg2 = lane >> 5;

    // bijective XCD swizzle (same as round 3)
    const int f = blockIdx.y * 16 + blockIdx.x;
    const int g = (f & 7) * 64 + (f >> 3);
    const int qt = g & 15, bh = g >> 4;
    const int b = bh >> 4, h = bh & 15;
    const size_t seq0 = (size_t)b * SEQ;
    const int col0 = h * 64;

    // Q fragments (B-operand): q = lane&31, k = kc*16 + lg2*8 + j
    const int qrow = qt * 128 + wv * 32 + l31;
    bf16x8 qh[4], ql[4];
    #pragma unroll
    for (int kc = 0; kc < 4; ++kc) {
        const size_t off = (seq0 + qrow) * DM + col0 + kc * 16 + lg2 * 8;
        qh[kc] = *(const bf16x8*)(Qhi + off);
        ql[kc] = *(const bf16x8*)(Qlo + off);
    }

    f32x16 accT0 = {}, accT1 = {};        // O^T, d-blocks 0/1; col=q, row=d
    float m_run = -1e30f, l_run = 0.f;    // l is lane-partial (own 32 keys)

    // staging: thread covers rows sr, sr+32, 16B chunk sc8
    const int sr = tid >> 3, sc8 = (tid & 7) * 8;

    bf16x8 gkh[2], gkl[2], gvv[2];
    #pragma unroll
    for (int p = 0; p < 2; ++p) {
        const int row = sr + 32 * p;
        const size_t koff = (seq0 + row) * DM + col0 + sc8;
        gkh[p] = *(const bf16x8*)(Khi + koff);
        gkl[p] = *(const bf16x8*)(Klo + koff);
        gvv[p] = *(const bf16x8*)(Vt + (size_t)(col0 + row) * 4096 + seq0 + sc8);
    }

    for (int kt = 0; kt < SEQ; kt += 64) {
        __syncthreads();
        #pragma unroll
        for (int p = 0; p < 2; ++p) {
            const int row = sr + 32 * p;
            const int wi = row * 64 + (sc8 ^ ((row & 7) << 3));
            *(bf16x8*)(Ksh + wi) = gkh[p];
            *(bf16x8*)(Ksl + wi) = gkl[p];
            *(bf16x8*)(Vsm + wi) = gvv[p];
        }
        __syncthreads();

        // issue next tile's global loads (latency hides under compute)
        {
            const int ktn = (kt + 64 < SEQ) ? kt + 64 : kt;
            #pragma unroll
            for (int p = 0; p < 2; ++p) {
                const int row = sr + 32 * p;
                const size_t koff = (seq0 + ktn + row) * DM + col0 + sc8;
                gkh[p] = *(const bf16x8*)(Khi + koff);
                gkl[p] = *(const bf16x8*)(Klo + koff);
                gvv[p] = *(const bf16x8*)(Vt + (size_t)(col0 + row) * 4096 + seq0 + ktn + sc8);
            }
        }

        // ---- S^T = K Q^T (hi/lo 3-MFMA), keys 0..31 -> s0, 32..63 -> s1
        f32x16 s0 = {}, s1 = {};
        #pragma unroll
        for (int kc = 0; kc < 4; ++kc) {
            const int c = kc * 2 + lg2;
            bf16x8 kh0 = lds_rd(Ksh, l31,      c);
            bf16x8 kh1 = lds_rd(Ksh, l31 + 32, c);
            bf16x8 kl0 = lds_rd(Ksl, l31,      c);
            bf16x8 kl1 = lds_rd(Ksl, l31 + 32, c);
            s0 = mfma32(kh0, qh[kc], s0);
            s0 = mfma32(kl0, qh[kc], s0);
            s0 = mfma32(kh0, ql[kc], s0);
            s1 = mfma32(kh1, qh[kc], s1);
            s1 = mfma32(kl1, qh[kc], s1);
            s1 = mfma32(kh1, ql[kc], s1);
        }

        // ---- in-register online softmax (q = lane&31 for all 32 values)
        float mx = -1e30f;
        #pragma unroll
        for (int i = 0; i < 16; ++i) {
            s0[i] *= 0.125f; s1[i] *= 0.125f;
            mx = fmaxf(mx, fmaxf(s0[i], s1[i]));
        }
        mx = fmaxf(mx, __shfl_xor(mx, 32));
        const float mnew  = fmaxf(m_run, mx);
        const float alpha = __expf(m_run - mnew);
        m_run = mnew;
        float rs = 0.f;
        #pragma unroll
        for (int i = 0; i < 16; ++i) {
            float p0 = __expf(s0[i] - mnew), p1 = __expf(s1[i] - mnew);
            s0[i] = p0; s1[i] = p1; rs += p0 + p1;
        }
        l_run = l_run * alpha + rs;
        #pragma unroll
        for (int i = 0; i < 16; ++i) { accT0[i] *= alpha; accT1[i] *= alpha; }

        // ---- pack P to bf16 pairs; exchange halves to build PV B-frags.
        // Lane holds keys kk = (reg&3)+8*(reg>>2)+4*lg2 (+32 for s1).
        // Frag t needs keys 16t+8*lg2+0..7: own block m=(2t+lg2)&3 (4 keys)
        // + partner lane^32's same block (other 4 keys).
        unsigned pk[2][4][2];
        #pragma unroll
        for (int m = 0; m < 4; ++m) {
            pk[0][m][0] = cvtpk(s0[4 * m],     s0[4 * m + 1]);
            pk[0][m][1] = cvtpk(s0[4 * m + 2], s0[4 * m + 3]);
            pk[1][m][0] = cvtpk(s1[4 * m],     s1[4 * m + 1]);
            pk[1][m][1] = cvtpk(s1[4 * m + 2], s1[4 * m + 3]);
        }
        bf16x8 pa[4];
        #pragma unroll
        for (int bb = 0; bb < 2; ++bb)
            #pragma unroll
            for (int u = 0; u < 2; ++u) {
                const unsigned pe0 = pk[bb][2 * u][0],     pe1 = pk[bb][2 * u][1];
                const unsigned po0 = pk[bb][2 * u + 1][0], po1 = pk[bb][2 * u + 1][1];
                const unsigned sd0 = lg2 ? pe0 : po0;   // what partner needs
                const unsigned sd1 = lg2 ? pe1 : po1;
                const unsigned rc0 = (unsigned)__shfl_xor((int)sd0, 32);
                const unsigned rc1 = (unsigned)__shfl_xor((int)sd1, 32);
                const unsigned a0 = lg2 ? rc0 : pe0;    // keys +0..1
                const unsigned a1 = lg2 ? rc1 : pe1;    // keys +2..3
                const unsigned a2 = lg2 ? po0 : rc0;    // keys +4..5
                const unsigned a3 = lg2 ? po1 : rc1;    // keys +6..7
                pa[2 * bb + u] = pack4(a0, a1, a2, a3);
            }

        // ---- O^T += V^T P : A=V^T frag (d=lane&31), B=pa (q=lane&31)
        #pragma unroll
        for (int t = 0; t < 4; ++t) {
            const int c = t * 2 + lg2;
            bf16x8 v0 = lds_rd(Vsm, l31,      c);
            bf16x8 v1 = lds_rd(Vsm, l31 + 32, c);
            accT0 = mfma32(v0, pa[t], accT0);
            accT1 = mfma32(v1, pa[t], accT1);
        }
    }

    // ---- epilogue: combine lane-partial l, write O[q][d]
    const float lt  = l_run + __shfl_xor(l_run, 32);
    const float inv = 1.0f / lt;
    #pragma unroll
    for (int reg = 0; reg < 16; ++reg) {
        const int d = (reg & 3) + 8 * (reg >> 2) + 4 * lg2;
        Mrg[(seq0 + qrow) * DM + col0 + d]      = f2bf(accT0[reg] * inv);
        Mrg[(seq0 + qrow) * DM + col0 + d + 32] = f2bf(accT1[reg] * inv);
    }
}

// ------------------------------------------------------------------
extern "C" void kernel_launch(void* const* d_in, const int* in_sizes, int n_in,
                              void* d_out, int out_size, void* d_ws, size_t ws_size,
                              hipStream_t stream)
{
    const float* queries = (const float*)d_in[0];
    const float* keys    = (const float*)d_in[1];
    const float* values  = (const float*)d_in[2];
    const float* w_q = (const float*)d_in[3];
    const float* b_q = (const float*)d_in[4];
    const float* w_k = (const float*)d_in[5];
    const float* b_k = (const float*)d_in[6];
    const float* w_v = (const float*)d_in[7];
    const float* b_v = (const float*)d_in[8];
    const float* w_o = (const float*)d_in[9];
    const float* b_o = (const float*)d_in[10];

    const size_t MB = 1u << 20;
    char* ws = (char*)d_ws;
    ushort_t* q_hi   = (ushort_t*)(ws);
    ushort_t* q_lo   = (ushort_t*)(ws + 8 * MB);
    ushort_t* Khi    = (ushort_t*)(ws);
    ushort_t* Klo    = (ushort_t*)(ws + 8 * MB);
    ushort_t* Qhi    = (ushort_t*)(ws + 16 * MB);
    ushort_t* Qlo    = (ushort_t*)(ws + 24 * MB);
    ushort_t* Vt     = (ushort_t*)(ws + 32 * MB);
    ushort_t* Mb     = (ushort_t*)(ws + 40 * MB);
    ushort_t* wsp_hi = (ushort_t*)(ws + 40 * MB);
    ushort_t* wsp_lo = (ushort_t*)(ws + 42 * MB);
    ushort_t* k_hi   = (ushort_t*)d_out;                    // keys split lives in d_out
    ushort_t* k_lo   = (ushort_t*)((char*)d_out + 8 * MB);  // (dead before O-proj writes)

    const int n4_act = 4096 * 1024 / 4, n4_w = 1024 * 1024 / 4;
    dim3 blk(256);

    hipLaunchKernelGGL(split_kernel, dim3(2048), blk, 0, stream, queries, q_hi, q_lo, n4_act);
    hipLaunchKernelGGL(split_kernel, dim3(2048), blk, 0, stream, keys, k_hi, k_lo, n4_act);
    hipLaunchKernelGGL(split_kernel, dim3(1024), blk, 0, stream, w_q, wsp_hi, wsp_lo, n4_w);
    hipLaunchKernelGGL(gemm_split, dim3(16, 32), blk, 0, stream,
                       q_hi, q_lo, wsp_hi, wsp_lo, b_q, Qhi, Qlo);
    hipLaunchKernelGGL(split_kernel, dim3(1024), blk, 0, stream, w_k, wsp_hi, wsp_lo, n4_w);
    hipLaunchKernelGGL(gemm_split, dim3(16, 32), blk, 0, stream,
                       k_hi, k_lo, wsp_hi, wsp_lo, b_k, Khi, Klo);
    hipLaunchKernelGGL((gemm_mixed<0>), dim3(64, 8), blk, 0, stream, w_v, values, b_v, Vt);
    hipLaunchKernelGGL(attn4_kernel, dim3(16, 32), blk, 0, stream, Qhi, Qlo, Khi, Klo, Vt, Mb);
    hipLaunchKernelGGL((gemm_mixed<1>), dim3(16, 32), blk, 0, stream, Mb, w_o, b_o, (float*)d_out);
}